// Round 1
// baseline (675.154 us; speedup 1.0000x reference)
//
#include <hip/hip_runtime.h>
#include <math.h>

#define HH 256
#define WW 256
#define HW (HH * WW)
#define TB 10

__device__ __forceinline__ float sp10(float x) {
    float z = 10.0f * x;
    return (fmaxf(z, 0.0f) + log1pf(expf(-fabsf(z)))) * 0.1f;
}

// ---------------------------------------------------------------------------
// Weight transpose: OIHW -> [ci][tap][co] (co contiguous) for scalar-load use.
// wt3 additionally picks only the 54 needed channels, layout [ci][tap][j*6+g]
// where j = tt-1 (tt=1..9), g = param group (kappa,m1d,m2d,gamma,vx,vy).
// ---------------------------------------------------------------------------
__global__ __launch_bounds__(256) void transpose_weights(
    const float* __restrict__ w1, const float* __restrict__ w2,
    const float* __restrict__ w3,
    float* __restrict__ wt1, float* __restrict__ wt2, float* __restrict__ wt3)
{
    int idx = blockIdx.x * 256 + threadIdx.x;
    if (idx < 2880) {               // conv1: (32,10,3,3) -> [ci<10][tap<9][co<32]
        int ci = idx / 288; int rem = idx - ci * 288;
        int tap = rem / 32; int co = rem - tap * 32;
        wt1[idx] = w1[co * 90 + ci * 9 + tap];
    }
    if (idx < 18432) {              // conv2: (64,32,3,3) -> [ci<32][tap<9][co<64]
        int ci = idx / 576; int rem = idx - ci * 576;
        int tap = rem / 64; int co = rem - tap * 64;
        wt2[idx] = w2[co * 288 + ci * 9 + tap];
    }
    if (idx < 31104) {              // conv3: (60,64,3,3) -> [ci<64][tap<9][54]
        int ci = idx / 486; int rem = idx - ci * 486;
        int tap = rem / 54; int j54 = rem - tap * 54;
        int tt = j54 / 6 + 1;       // time 1..9
        int g  = j54 - (tt - 1) * 6; // group 0..5
        wt3[idx] = w3[(g * 10 + tt) * 576 + ci * 9 + tap];
    }
}

// ---------------------------------------------------------------------------
// Generic direct 3x3 SAME conv: 16x16 output tile / block (256 thr), LDS-staged
// (18x18 x CIN) input tile, each thread accumulates all COUT channels.
// ---------------------------------------------------------------------------
template <int CIN, int COUT, bool RELU_IN>
__global__ __launch_bounds__(256) void conv3x3_k(
    const float* __restrict__ in, const float* __restrict__ wt,
    float* __restrict__ out)
{
    __shared__ float tile[CIN * 324];
    const int tx = threadIdx.x & 15, ty = threadIdx.x >> 4;
    const int h0 = blockIdx.y * 16, w0 = blockIdx.x * 16;
    const int bz = blockIdx.z;
    const float* inb = in + (size_t)bz * CIN * HW;

    for (int i = threadIdx.x; i < CIN * 324; i += 256) {
        int ci = i / 324; int r = i - ci * 324;
        int yy = r / 18; int xx = r - yy * 18;
        int gy = h0 + yy - 1, gx = w0 + xx - 1;
        float v = 0.0f;
        if (gy >= 0 && gy < HH && gx >= 0 && gx < WW)
            v = inb[ci * HW + gy * WW + gx];
        if (RELU_IN) v = fmaxf(v, 0.0f);
        tile[i] = v;
    }
    __syncthreads();

    float acc[COUT];
#pragma unroll
    for (int c = 0; c < COUT; ++c) acc[c] = 0.0f;

    for (int ci = 0; ci < CIN; ++ci) {
        const float* tp = &tile[ci * 324 + ty * 18 + tx];
        float v[9];
        v[0] = tp[0];  v[1] = tp[1];  v[2] = tp[2];
        v[3] = tp[18]; v[4] = tp[19]; v[5] = tp[20];
        v[6] = tp[36]; v[7] = tp[37]; v[8] = tp[38];
        const float* wp = wt + ci * 9 * COUT;
#pragma unroll
        for (int tap = 0; tap < 9; ++tap)
#pragma unroll
            for (int co = 0; co < COUT; ++co)
                acc[co] = fmaf(wp[tap * COUT + co], v[tap], acc[co]);
    }

    float* ob = out + (size_t)bz * COUT * HW + (size_t)(h0 + ty) * WW + (w0 + tx);
#pragma unroll
    for (int co = 0; co < COUT; ++co) ob[(size_t)co * HW] = acc[co];
}

// ---------------------------------------------------------------------------
// conv3 (64 -> 54 needed channels) fused with guide/w_ker/PAC epilogue.
// Stages p2 in two 32-channel halves (LDS 41.5 KB).
// ---------------------------------------------------------------------------
__global__ __launch_bounds__(256) void conv3_final_k(
    const float* __restrict__ p2, const float* __restrict__ wt3,
    const float* __restrict__ x, const float* __restrict__ pacw,
    const float* __restrict__ pacb, float* __restrict__ out)
{
    __shared__ float tile[32 * 324];
    const int tx = threadIdx.x & 15, ty = threadIdx.x >> 4;
    const int h0 = blockIdx.y * 16, w0 = blockIdx.x * 16;
    const int bz = blockIdx.z;
    const float* pbase = p2 + (size_t)bz * 64 * HW;

    float acc[54];
#pragma unroll
    for (int c = 0; c < 54; ++c) acc[c] = 0.0f;

    for (int half = 0; half < 2; ++half) {
        const float* inb = pbase + (size_t)half * 32 * HW;
        for (int i = threadIdx.x; i < 32 * 324; i += 256) {
            int ci = i / 324; int r = i - ci * 324;
            int yy = r / 18; int xx = r - yy * 18;
            int gy = h0 + yy - 1, gx = w0 + xx - 1;
            float v = 0.0f;
            if (gy >= 0 && gy < HH && gx >= 0 && gx < WW)
                v = inb[ci * HW + gy * WW + gx];
            tile[i] = v;
        }
        __syncthreads();
        const float* wh = wt3 + (size_t)half * 32 * 486;
        for (int ci = 0; ci < 32; ++ci) {
            const float* tp = &tile[ci * 324 + ty * 18 + tx];
            float v[9];
            v[0] = tp[0];  v[1] = tp[1];  v[2] = tp[2];
            v[3] = tp[18]; v[4] = tp[19]; v[5] = tp[20];
            v[6] = tp[36]; v[7] = tp[37]; v[8] = tp[38];
            const float* wp = wh + ci * 486;
#pragma unroll
            for (int tap = 0; tap < 9; ++tap)
#pragma unroll
                for (int co = 0; co < 54; ++co)
                    acc[co] = fmaf(wp[tap * 54 + co], v[tap], acc[co]);
        }
        __syncthreads();
    }

    // ---- epilogue: guide -> w_ker -> PAC against x neighborhood ----
    float pw[9];
#pragma unroll
    for (int k = 0; k < 9; ++k) pw[k] = pacw[k];
    const float pbias = pacb[0];
    const int h = h0 + ty, w = w0 + tx;
    const float* xb = x + (size_t)bz * TB * HW;
    float* ob = out + (size_t)bz * TB * HW;

#pragma unroll
    for (int j = 0; j < 9; ++j) {
        const int tt = j + 1;
        float kappa = sp10(acc[j * 6 + 0]);
        float m1d   = acc[j * 6 + 1];
        float m2d   = acc[j * 6 + 2];
        float gamma = sp10(acc[j * 6 + 3]);
        float vx    = acc[j * 6 + 4];
        float vy    = acc[j * 6 + 5];
        float H11 = gamma + vx * vx;
        float H22 = gamma + vy * vy;
        float H12 = vx * vy;
        float iH11 = 1.0f / H11;
        float iH22 = 1.0f / H22;
        float wk[9];
        wk[0] = -0.5f * H12;  wk[1] = -iH22 + m1d;  wk[2] = 0.5f * H12;
        wk[3] = -iH11 - m2d;
        wk[4] = kappa + 2.0f * H11 + 2.0f * H22 + 1.0f;
        wk[5] = -iH11 + m2d;
        wk[6] = 0.5f * H12;   wk[7] = -iH22 - m1d;  wk[8] = -0.5f * H12;

        const float* xc = xb + (size_t)tt * HW;
        float s = 0.0f;
#pragma unroll
        for (int dy = 0; dy < 3; ++dy)
#pragma unroll
            for (int dx = 0; dx < 3; ++dx) {
                int gy = h + dy - 1, gx = w + dx - 1;
                float xv = (gy >= 0 && gy < HH && gx >= 0 && gx < WW)
                               ? xc[gy * WW + gx] : 0.0f;
                s = fmaf(pw[dy * 3 + dx] * wk[dy * 3 + dx], xv, s);
            }
        ob[(size_t)j * HW + (size_t)h * WW + w] = s + pbias;
    }
    ob[(size_t)9 * HW + (size_t)h * WW + w] = 0.0f;  // zero last channel
}

// ---------------------------------------------------------------------------
extern "C" void kernel_launch(void* const* d_in, const int* in_sizes, int n_in,
                              void* d_out, int out_size, void* d_ws, size_t ws_size,
                              hipStream_t stream)
{
    const float* x    = (const float*)d_in[0];
    const float* w1   = (const float*)d_in[1];
    const float* w2   = (const float*)d_in[2];
    const float* w3   = (const float*)d_in[3];
    const float* pacw = (const float*)d_in[4];
    const float* pacb = (const float*)d_in[5];
    float* out = (float*)d_out;
    float* ws  = (float*)d_ws;

    float* wt1  = ws;            // 2880 floats
    float* wt2  = ws + 2880;     // 18432 floats
    float* wt3  = ws + 21312;    // 31104 floats
    float* bufs = ws + 52480;    // aligned scratch for p1/p2

    transpose_weights<<<dim3((52416 + 255) / 256), dim3(256), 0, stream>>>(
        w1, w2, w3, wt1, wt2, wt3);

    const size_t need_full =
        ((size_t)52480 + (size_t)4 * 32 * HW + (size_t)4 * 64 * HW) * sizeof(float);
    dim3 blk(256);
    if (ws_size >= need_full) {
        float* p1 = bufs;                        // 4*32*HW
        float* p2 = p1 + (size_t)4 * 32 * HW;    // 4*64*HW
        dim3 grid(16, 16, 4);
        conv3x3_k<10, 32, true><<<grid, blk, 0, stream>>>(x, wt1, p1);
        conv3x3_k<32, 64, true><<<grid, blk, 0, stream>>>(p1, wt2, p2);
        conv3_final_k<<<grid, blk, 0, stream>>>(p2, wt3, x, pacw, pacb, out);
    } else {
        // small-workspace fallback: loop batches, reuse p1/p2 (25.4 MB total)
        float* p1 = bufs;
        float* p2 = p1 + (size_t)32 * HW;
        dim3 grid(16, 16, 1);
        for (int b = 0; b < 4; ++b) {
            const float* xb = x + (size_t)b * TB * HW;
            float* outb = out + (size_t)b * TB * HW;
            conv3x3_k<10, 32, true><<<grid, blk, 0, stream>>>(xb, wt1, p1);
            conv3x3_k<32, 64, true><<<grid, blk, 0, stream>>>(p1, wt2, p2);
            conv3_final_k<<<grid, blk, 0, stream>>>(p2, wt3, xb, pacw, pacb, outb);
        }
    }
}

// Round 2
// 505.061 us; speedup vs baseline: 1.3368x; 1.3368x over previous
//
#include <hip/hip_runtime.h>
#include <math.h>

#define HH 256
#define WW 256
#define HW (HH * WW)
#define TB 10

__device__ __forceinline__ float sp10(float x) {
    float z = 10.0f * x;
    return (fmaxf(z, 0.0f) + log1pf(expf(-fabsf(z)))) * 0.1f;
}

// ---------------------------------------------------------------------------
// Weight transpose: OIHW -> [ci][tap][co] (co contiguous) for scalar-load use.
// wt3 picks only the 54 needed channels: [ci][tap][(tt-1)*6+g].
// ---------------------------------------------------------------------------
__global__ __launch_bounds__(256) void transpose_weights(
    const float* __restrict__ w1, const float* __restrict__ w2,
    const float* __restrict__ w3,
    float* __restrict__ wt1, float* __restrict__ wt2, float* __restrict__ wt3)
{
    int idx = blockIdx.x * 256 + threadIdx.x;
    if (idx < 2880) {               // conv1: (32,10,3,3) -> [ci<10][tap<9][co<32]
        int ci = idx / 288; int rem = idx - ci * 288;
        int tap = rem / 32; int co = rem - tap * 32;
        wt1[idx] = w1[co * 90 + ci * 9 + tap];
    }
    if (idx < 18432) {              // conv2: (64,32,3,3) -> [ci<32][tap<9][co<64]
        int ci = idx / 576; int rem = idx - ci * 576;
        int tap = rem / 64; int co = rem - tap * 64;
        wt2[idx] = w2[co * 288 + ci * 9 + tap];
    }
    if (idx < 31104) {              // conv3: (60,64,3,3) -> [ci<64][tap<9][54]
        int ci = idx / 486; int rem = idx - ci * 486;
        int tap = rem / 54; int j54 = rem - tap * 54;
        int tt = j54 / 6 + 1;
        int g  = j54 - (tt - 1) * 6;
        wt3[idx] = w3[(g * 10 + tt) * 576 + ci * 9 + tap];
    }
}

// ---------------------------------------------------------------------------
// Direct 3x3 SAME conv, ci-CHUNKED LDS staging (CHUNK*324 floats = 20.7 KB at
// CHUNK=16) so >=4 blocks/CU stay resident to hide SMEM weight-load latency.
// 16x16 output tile / 256-thread block; each thread accumulates all COUT.
// ---------------------------------------------------------------------------
template <int CIN, int CHUNK, int COUT, bool RELU_IN>
__global__ __launch_bounds__(256, 4) void conv3x3_k(
    const float* __restrict__ in, const float* __restrict__ wt,
    float* __restrict__ out)
{
    __shared__ float tile[CHUNK * 324];
    const int tx = threadIdx.x & 15, ty = threadIdx.x >> 4;
    const int h0 = blockIdx.y * 16, w0 = blockIdx.x * 16;
    const int bz = blockIdx.z;
    const float* inb = in + (size_t)bz * CIN * HW;

    float acc[COUT];
#pragma unroll
    for (int c = 0; c < COUT; ++c) acc[c] = 0.0f;

    for (int c0 = 0; c0 < CIN; c0 += CHUNK) {
        if (c0 != 0) __syncthreads();
        const float* inc = inb + (size_t)c0 * HW;
        for (int i = threadIdx.x; i < CHUNK * 324; i += 256) {
            int ci = i / 324; int r = i - ci * 324;
            int yy = r / 18; int xx = r - yy * 18;
            int gy = h0 + yy - 1, gx = w0 + xx - 1;
            float v = 0.0f;
            if (gy >= 0 && gy < HH && gx >= 0 && gx < WW)
                v = inc[ci * HW + gy * WW + gx];
            if (RELU_IN) v = fmaxf(v, 0.0f);
            tile[i] = v;
        }
        __syncthreads();

        for (int ci = 0; ci < CHUNK; ++ci) {
            const float* tp = &tile[ci * 324 + ty * 18 + tx];
            float v[9];
            v[0] = tp[0];  v[1] = tp[1];  v[2] = tp[2];
            v[3] = tp[18]; v[4] = tp[19]; v[5] = tp[20];
            v[6] = tp[36]; v[7] = tp[37]; v[8] = tp[38];
            const float* wp = wt + (size_t)(c0 + ci) * 9 * COUT;
#pragma unroll
            for (int tap = 0; tap < 9; ++tap)
#pragma unroll
                for (int co = 0; co < COUT; ++co)
                    acc[co] = fmaf(wp[tap * COUT + co], v[tap], acc[co]);
        }
    }

    float* ob = out + (size_t)bz * COUT * HW + (size_t)(h0 + ty) * WW + (w0 + tx);
#pragma unroll
    for (int co = 0; co < COUT; ++co) ob[(size_t)co * HW] = acc[co];
}

// ---------------------------------------------------------------------------
// conv3 (64 -> 54 needed channels) fused with guide/w_ker/PAC epilogue.
// ci chunked by 16 (LDS 20.7 KB) for occupancy.
// ---------------------------------------------------------------------------
__global__ __launch_bounds__(256, 4) void conv3_final_k(
    const float* __restrict__ p2, const float* __restrict__ wt3,
    const float* __restrict__ x, const float* __restrict__ pacw,
    const float* __restrict__ pacb, float* __restrict__ out)
{
    __shared__ float tile[16 * 324];
    const int tx = threadIdx.x & 15, ty = threadIdx.x >> 4;
    const int h0 = blockIdx.y * 16, w0 = blockIdx.x * 16;
    const int bz = blockIdx.z;
    const float* pbase = p2 + (size_t)bz * 64 * HW;

    float acc[54];
#pragma unroll
    for (int c = 0; c < 54; ++c) acc[c] = 0.0f;

    for (int c0 = 0; c0 < 64; c0 += 16) {
        if (c0 != 0) __syncthreads();
        const float* inc = pbase + (size_t)c0 * HW;
        for (int i = threadIdx.x; i < 16 * 324; i += 256) {
            int ci = i / 324; int r = i - ci * 324;
            int yy = r / 18; int xx = r - yy * 18;
            int gy = h0 + yy - 1, gx = w0 + xx - 1;
            float v = 0.0f;
            if (gy >= 0 && gy < HH && gx >= 0 && gx < WW)
                v = inc[ci * HW + gy * WW + gx];
            tile[i] = v;
        }
        __syncthreads();

        for (int ci = 0; ci < 16; ++ci) {
            const float* tp = &tile[ci * 324 + ty * 18 + tx];
            float v[9];
            v[0] = tp[0];  v[1] = tp[1];  v[2] = tp[2];
            v[3] = tp[18]; v[4] = tp[19]; v[5] = tp[20];
            v[6] = tp[36]; v[7] = tp[37]; v[8] = tp[38];
            const float* wp = wt3 + (size_t)(c0 + ci) * 486;
#pragma unroll
            for (int tap = 0; tap < 9; ++tap)
#pragma unroll
                for (int co = 0; co < 54; ++co)
                    acc[co] = fmaf(wp[tap * 54 + co], v[tap], acc[co]);
        }
    }

    // ---- epilogue: guide -> w_ker -> PAC against x neighborhood ----
    float pw[9];
#pragma unroll
    for (int k = 0; k < 9; ++k) pw[k] = pacw[k];
    const float pbias = pacb[0];
    const int h = h0 + ty, w = w0 + tx;
    const float* xb = x + (size_t)bz * TB * HW;
    float* ob = out + (size_t)bz * TB * HW;

#pragma unroll
    for (int j = 0; j < 9; ++j) {
        const int tt = j + 1;
        float kappa = sp10(acc[j * 6 + 0]);
        float m1d   = acc[j * 6 + 1];
        float m2d   = acc[j * 6 + 2];
        float gamma = sp10(acc[j * 6 + 3]);
        float vx    = acc[j * 6 + 4];
        float vy    = acc[j * 6 + 5];
        float H11 = gamma + vx * vx;
        float H22 = gamma + vy * vy;
        float H12 = vx * vy;
        float iH11 = 1.0f / H11;
        float iH22 = 1.0f / H22;
        float wk[9];
        wk[0] = -0.5f * H12;  wk[1] = -iH22 + m1d;  wk[2] = 0.5f * H12;
        wk[3] = -iH11 - m2d;
        wk[4] = kappa + 2.0f * H11 + 2.0f * H22 + 1.0f;
        wk[5] = -iH11 + m2d;
        wk[6] = 0.5f * H12;   wk[7] = -iH22 - m1d;  wk[8] = -0.5f * H12;

        const float* xc = xb + (size_t)tt * HW;
        float s = 0.0f;
#pragma unroll
        for (int dy = 0; dy < 3; ++dy)
#pragma unroll
            for (int dx = 0; dx < 3; ++dx) {
                int gy = h + dy - 1, gx = w + dx - 1;
                float xv = (gy >= 0 && gy < HH && gx >= 0 && gx < WW)
                               ? xc[gy * WW + gx] : 0.0f;
                s = fmaf(pw[dy * 3 + dx] * wk[dy * 3 + dx], xv, s);
            }
        ob[(size_t)j * HW + (size_t)h * WW + w] = s + pbias;
    }
    ob[(size_t)9 * HW + (size_t)h * WW + w] = 0.0f;
}

// ---------------------------------------------------------------------------
extern "C" void kernel_launch(void* const* d_in, const int* in_sizes, int n_in,
                              void* d_out, int out_size, void* d_ws, size_t ws_size,
                              hipStream_t stream)
{
    const float* x    = (const float*)d_in[0];
    const float* w1   = (const float*)d_in[1];
    const float* w2   = (const float*)d_in[2];
    const float* w3   = (const float*)d_in[3];
    const float* pacw = (const float*)d_in[4];
    const float* pacb = (const float*)d_in[5];
    float* out = (float*)d_out;
    float* ws  = (float*)d_ws;

    float* wt1  = ws;            // 2880 floats
    float* wt2  = ws + 2880;     // 18432 floats
    float* wt3  = ws + 21312;    // 31104 floats
    float* bufs = ws + 52480;    // scratch for p1/p2

    transpose_weights<<<dim3((52416 + 255) / 256), dim3(256), 0, stream>>>(
        w1, w2, w3, wt1, wt2, wt3);

    const size_t need_full =
        ((size_t)52480 + (size_t)4 * 32 * HW + (size_t)4 * 64 * HW) * sizeof(float);
    dim3 blk(256);
    if (ws_size >= need_full) {
        float* p1 = bufs;                        // 4*32*HW
        float* p2 = p1 + (size_t)4 * 32 * HW;    // 4*64*HW
        dim3 grid(16, 16, 4);
        conv3x3_k<10, 10, 32, true><<<grid, blk, 0, stream>>>(x, wt1, p1);
        conv3x3_k<32, 16, 64, true><<<grid, blk, 0, stream>>>(p1, wt2, p2);
        conv3_final_k<<<grid, blk, 0, stream>>>(p2, wt3, x, pacw, pacb, out);
    } else {
        float* p1 = bufs;
        float* p2 = p1 + (size_t)32 * HW;
        dim3 grid(16, 16, 1);
        for (int b = 0; b < 4; ++b) {
            const float* xb = x + (size_t)b * TB * HW;
            float* outb = out + (size_t)b * TB * HW;
            conv3x3_k<10, 10, 32, true><<<grid, blk, 0, stream>>>(xb, wt1, p1);
            conv3x3_k<32, 16, 64, true><<<grid, blk, 0, stream>>>(p1, wt2, p2);
            conv3_final_k<<<grid, blk, 0, stream>>>(p2, wt3, xb, pacw, pacb, outb);
        }
    }
}